// Round 12
// baseline (389.184 us; speedup 1.0000x reference)
//
#include <hip/hip_runtime.h>
#include <math.h>
#include <cstddef>

#define NN 4096
#define DIMC 128
#define NHEADS 8
#define NE 65536

typedef unsigned short ushort_t;
typedef short bs8 __attribute__((ext_vector_type(8)));
typedef float f32x16 __attribute__((ext_vector_type(16)));
typedef _Float16 h4 __attribute__((ext_vector_type(4)));
typedef __fp16 fp16x2 __attribute__((ext_vector_type(2)));
typedef float f4t __attribute__((ext_vector_type(4)));

__device__ __forceinline__ float b2f(ushort_t u){
  unsigned int i = ((unsigned int)u)<<16; float f;
  __builtin_memcpy(&f,&i,4); return f;
}
__device__ __forceinline__ ushort_t f2b(float f){
  unsigned int x; __builtin_memcpy(&x,&f,4);
  unsigned int r = x + 0x7fffu + ((x>>16)&1u);
  return (ushort_t)(r>>16);
}
__device__ __forceinline__ float bdot8(uint4 a, uint4 b){
  unsigned int ua[4]={a.x,a.y,a.z,a.w}, ub[4]={b.x,b.y,b.z,b.w};
  float s=0.f;
  #pragma unroll
  for (int i=0;i<4;++i){
    unsigned int al=ua[i]<<16, ah=ua[i]&0xffff0000u, bl=ub[i]<<16, bh=ub[i]&0xffff0000u;
    float fa,fb,fc,fd;
    __builtin_memcpy(&fa,&al,4); __builtin_memcpy(&fb,&ah,4);
    __builtin_memcpy(&fc,&bl,4); __builtin_memcpy(&fd,&bh,4);
    s += fa*fc + fb*fd;
  }
  return s;
}
// bf16x8 (uint4) dot fp32x8 (two float4s)
__device__ __forceinline__ float bfdot8v(uint4 a, float4 e0, float4 e1){
  unsigned int ua[4]={a.x,a.y,a.z,a.w};
  float eb[8]={e0.x,e0.y,e0.z,e0.w,e1.x,e1.y,e1.z,e1.w};
  float s=0.f;
  #pragma unroll
  for (int i=0;i<4;++i){
    unsigned int al=ua[i]<<16, ah=ua[i]&0xffff0000u;
    float fa,fb;
    __builtin_memcpy(&fa,&al,4); __builtin_memcpy(&fb,&ah,4);
    s += fa*eb[2*i] + fb*eb[2*i+1];
  }
  return s;
}

// ---------------- scan (256-thread version, runs as a spare block in qkv GEMM) ----------------
__device__ void scan256(const int* __restrict__ cnt, int* __restrict__ rows,
                        int* __restrict__ cursor){
  __shared__ int sums[256];
  int t = threadIdx.x;
  int base = t*16;
  int c[16]; int local=0;
  #pragma unroll
  for (int i=0;i<16;++i){ c[i]=cnt[base+i]; local+=c[i]; }
  sums[t]=local; __syncthreads();
  for (int off=1; off<256; off<<=1){
    int v = (t>=off)? sums[t-off] : 0; __syncthreads();
    sums[t]+=v; __syncthreads();
  }
  int r = sums[t]-local;
  #pragma unroll
  for (int i=0;i<16;++i){ rows[base+i]=r; cursor[base+i]=r; r+=c[i]; }
  if (t==255) rows[4096]=r;
}

// ---------------- LayerNorm: wave-per-row + fused count (ln1) / scatter (ln2) ----------------
// blocks [0,1024): LN of 4 rows each; if cnt!=null also one edge-count atomic per thread.
// blocks [1024,1280) (ln2 only): CSR scatter of 256 edges each -> packe only.
__global__ __launch_bounds__(256) void ln_kernel(const float* __restrict__ x,
    const float* __restrict__ g, const float* __restrict__ b, ushort_t* __restrict__ y,
    const int* __restrict__ ei, int* __restrict__ cnt,
    int* __restrict__ cursor, int* __restrict__ packe){
  int bb = blockIdx.x;
  if (bb >= 1024){
    int e = (bb-1024)*256 + threadIdx.x;
    int src = ei[e] & (NN-1), dst = ei[NE+e] & (NN-1);
    int pos = atomicAdd(&cursor[dst],1);
    if (pos >= 0 && pos < NE){
      packe[pos]=e|(src<<16);
    }
    return;
  }
  int n = bb*4 + (threadIdx.x>>6);
  int l = threadIdx.x & 63;
  int d0 = 2*l;
  float2 v = *(const float2*)&x[(size_t)n*DIMC + d0];
  float s = v.x+v.y;
  s += __shfl_xor(s,1); s += __shfl_xor(s,2); s += __shfl_xor(s,4);
  s += __shfl_xor(s,8); s += __shfl_xor(s,16); s += __shfl_xor(s,32);
  float mean = s*(1.0f/128.0f);
  float c0=v.x-mean, c1=v.y-mean;
  float q=c0*c0+c1*c1;
  q += __shfl_xor(q,1); q += __shfl_xor(q,2); q += __shfl_xor(q,4);
  q += __shfl_xor(q,8); q += __shfl_xor(q,16); q += __shfl_xor(q,32);
  float rinv = rsqrtf(q*(1.0f/128.0f)+1e-5f);
  float2 gv = *(const float2*)&g[d0];
  float2 bv = *(const float2*)&b[d0];
  unsigned int pk = ((unsigned int)f2b(c1*rinv*gv.y+bv.y)<<16) | (unsigned int)f2b(c0*rinv*gv.x+bv.x);
  *(unsigned int*)&y[(size_t)n*DIMC + d0] = pk;
  if (cnt){
    int gid = bb*256 + threadIdx.x;
    if (gid < NE) atomicAdd(&cnt[ei[NE+gid] & (NN-1)],1);
  }
}

// ---------------- one-shot weight convert: LDS-tiled coalesced transposes ----------------
#define QSCALE 0.36067376022224085f
__global__ __launch_bounds__(256) void megawcvt_kernel(
    const float* __restrict__ w_qkv, const float* __restrict__ w_o,
    const float* __restrict__ w_q, const float* __restrict__ w_k,
    const float* __restrict__ w_v, const float* __restrict__ w_e,
    const float* __restrict__ w_f1, const float* __restrict__ w_f2,
    const float* __restrict__ bq, const float* __restrict__ bk,
    const float* __restrict__ w_dyn, const float* __restrict__ b_qkv,
    ushort_t* __restrict__ WBqkv, ushort_t* __restrict__ WBo, ushort_t* __restrict__ WBG,
    ushort_t* __restrict__ WETB, ushort_t* __restrict__ WBf1, ushort_t* __restrict__ WBf2,
    ushort_t* __restrict__ WCAT, float* __restrict__ BCAT, ushort_t* __restrict__ WDYN,
    int* __restrict__ COUNT, float* __restrict__ BQKV)
{
  int b = blockIdx.x, tid = threadIdx.x;
  if (b < 1216){
    const float* src; int srcStride; ushort_t* dst; int dstStride;
    int n0, k0; float scale = 1.0f;
    if (b < 48){ int nt=b>>2, kt=b&3; src=w_qkv; srcStride=384; dst=WBqkv; dstStride=128;
      n0=nt*32; k0=kt*32; if (nt<4) scale=QSCALE; }
    else if (b < 64){ int l=b-48, nt=l>>2, kt=l&3; src=w_o; srcStride=128; dst=WBo; dstStride=128; n0=nt*32; k0=kt*32; }
    else if (b < 192){ int l=b-64, nt=l>>2, kt=l&3; src=w_q; srcStride=1024; dst=WBG; dstStride=128; n0=nt*32; k0=kt*32; }
    else if (b < 320){ int l=b-192, nt=l>>2, kt=l&3; src=w_k; srcStride=1024; dst=WBG+1024*128; dstStride=128; n0=nt*32; k0=kt*32; }
    else if (b < 448){ int l=b-320, nt=l>>2, kt=l&3; src=w_e; srcStride=1024; dst=WETB; dstStride=128; n0=nt*32; k0=kt*32; }
    else if (b < 704){ int l=b-448, nt=l>>2, kt=l&3; src=w_f1; srcStride=2048; dst=WBf1; dstStride=128; n0=nt*32; k0=kt*32; }
    else if (b < 960){ int l=b-704, nt=l>>6, kt=l&63; src=w_f2; srcStride=128; dst=WBf2; dstStride=2048; n0=nt*32; k0=kt*32; }
    else if (b < 1088){ int l=b-960, h=l>>4, tt=l&15, nt=tt>>2, kt=tt&3;
      src=w_v+h*128; srcStride=1024; dst=WCAT+h*128; dstStride=2048; n0=nt*32; k0=kt*32; scale=0.125f; }
    else { int l=b-1088, h=l>>4, tt=l&15, nt=tt>>2, kt=tt&3;
      src=w_e+h*128; srcStride=1024; dst=WCAT+1024+h*128; dstStride=2048; n0=nt*32; k0=kt*32; scale=0.125f; }
    __shared__ float lt[32*33];
    int rr = tid>>3, cg = (tid&7)*4;
    float4 v = *(const float4*)&src[(size_t)(k0+rr)*srcStride + n0 + cg];
    lt[rr*33+cg]=v.x; lt[rr*33+cg+1]=v.y; lt[rr*33+cg+2]=v.z; lt[rr*33+cg+3]=v.w;
    __syncthreads();
    ushort_t o[4] __attribute__((aligned(8)));
    #pragma unroll
    for (int j=0;j<4;++j) o[j] = f2b(lt[(cg+j)*33 + rr]*scale);
    *(ushort4*)&dst[(size_t)(n0+rr)*dstStride + k0 + cg] = *(ushort4*)o;
  } else {
    for (int id=(b-1216)*256+tid; id<39296; id += 40*256){
      if (id < 2048) BCAT[id] = (id<1024)? bq[id] : bk[id-1024];
      else if (id < 34816){ int l=id-2048; WDYN[l]=f2b(w_dyn[l]); }
      else if (id < 38912) COUNT[id-34816]=0;
      else { int l=id-38912; BQKV[l]=b_qkv[l]*((l<128)?QSCALE:1.0f); }
    }
  }
}

// ---------------- MFMA GEMM (fused V^T side-store; optional fused scan block) ----------------
template<int A_BF16, int C_MODE, int FUSE_SCAN>
__global__ __launch_bounds__(256) void mgemm_kernel(
    const void* __restrict__ Av, int lda, int strideA,
    const ushort_t* __restrict__ BT, int ldbt, int strideB,
    const float* __restrict__ bias,
    const float* __restrict__ res,
    void* __restrict__ Cv, int ldc, int strideC,
    int K, int act_gelu, _Float16* __restrict__ vtout,
    const int* __restrict__ scnt, int* __restrict__ srows, int* __restrict__ scur)
{
  if (FUSE_SCAN){
    if (blockIdx.x == gridDim.x-1){
      if (blockIdx.y==0 && blockIdx.z==0) scan256(scnt, srows, scur);
      return;
    }
  }
  int z = blockIdx.z;
  int m0 = blockIdx.y*128, n0 = blockIdx.x*64;
  int tid = threadIdx.x;
  int w = tid>>6, lane = tid&63;
  int kg = lane>>5;
  int ml = w*32 + (lane&31);
  int sw = (ml>>1)&3;
  __shared__ ushort_t As[128*32];
  const ushort_t* BTz = BT + (size_t)z*strideB;
  f32x16 acc[2];
  #pragma unroll
  for (int i=0;i<16;++i){ acc[0][i]=0.f; acc[1][i]=0.f; }

  for (int k0=0; k0<K; k0+=32){
    {
      int rr = tid>>1, kc = (tid&1)*16;
      int rowg = m0 + rr;
      ushort_t tmp[16] __attribute__((aligned(16)));
      if (A_BF16){
        const ushort_t* A = (const ushort_t*)Av + (size_t)z*strideA;
        uint4 u0 = *(const uint4*)&A[(size_t)rowg*lda + k0 + kc];
        uint4 u1 = *(const uint4*)&A[(size_t)rowg*lda + k0 + kc + 8];
        __builtin_memcpy(tmp, &u0, 16); __builtin_memcpy(tmp+8, &u1, 16);
      } else {
        const float* A = (const float*)Av + (size_t)z*strideA;
        const float* p = &A[(size_t)rowg*lda + k0 + kc];
        float4 f0=*(const float4*)p, f1=*(const float4*)(p+4);
        float4 f2v=*(const float4*)(p+8), f3=*(const float4*)(p+12);
        tmp[0]=f2b(f0.x); tmp[1]=f2b(f0.y); tmp[2]=f2b(f0.z); tmp[3]=f2b(f0.w);
        tmp[4]=f2b(f1.x); tmp[5]=f2b(f1.y); tmp[6]=f2b(f1.z); tmp[7]=f2b(f1.w);
        tmp[8]=f2b(f2v.x); tmp[9]=f2b(f2v.y); tmp[10]=f2b(f2v.z); tmp[11]=f2b(f2v.w);
        tmp[12]=f2b(f3.x); tmp[13]=f2b(f3.y); tmp[14]=f2b(f3.z); tmp[15]=f2b(f3.w);
      }
      int swr = (rr>>1)&3, c0 = kc>>3;
      *(uint4*)&As[rr*32 + (((c0  )^swr)*8)] = *(const uint4*)tmp;
      *(uint4*)&As[rr*32 + (((c0+1)^swr)*8)] = *(const uint4*)(tmp+8);
    }
    __syncthreads();
    bs8 a0 = *(bs8*)&As[ml*32 + (((0*2+kg)^sw)*8)];
    bs8 a1 = *(bs8*)&As[ml*32 + (((1*2+kg)^sw)*8)];
    #pragma unroll
    for (int nt=0; nt<2; ++nt){
      const ushort_t* bp = &BTz[(size_t)(n0 + nt*32 + (lane&31))*ldbt + k0 + kg*8];
      uint4 rb0 = *(const uint4*)bp;
      uint4 rb1 = *(const uint4*)(bp + 16);
      bs8 b0, b1;
      __builtin_memcpy(&b0, &rb0, 16); __builtin_memcpy(&b1, &rb1, 16);
      acc[nt] = __builtin_amdgcn_mfma_f32_32x32x16_bf16(a0, b0, acc[nt], 0,0,0);
      acc[nt] = __builtin_amdgcn_mfma_f32_32x32x16_bf16(a1, b1, acc[nt], 0,0,0);
    }
    __syncthreads();
  }
  #pragma unroll
  for (int nt=0; nt<2; ++nt){
    int col = n0 + nt*32 + (lane&31);
    float bv = bias ? bias[col] : 0.f;
    #pragma unroll
    for (int r=0; r<16; ++r){
      int rowl = (r&3) + 8*(r>>2) + 4*kg;
      int row = m0 + w*32 + rowl;
      float v = acc[nt][r] + bv;
      if (act_gelu) v = 0.5f*v*(1.0f+erff(v*0.70710678118654752f));
      if (res) v += res[(size_t)row*ldc + col];
      size_t idx = (size_t)z*strideC + (size_t)row*ldc + col;
      if (C_MODE==1)      ((ushort_t*)Cv)[idx] = f2b(v);
      else if (C_MODE==2){
        _Float16 hv = (_Float16)v;
        ((_Float16*)Cv)[idx] = hv;
        if (vtout && col>=256) vtout[(size_t)(col-256)*4096 + row] = hv;
      }
      else                ((float*)Cv)[idx]    = v;
    }
  }
}

// ---------------- Flash MHA: MFMA, m=0, 4 q-tiles per wave, K-split x8 ----------------
// Q pre-scaled by 0.25*log2(e), so p = 2^s (single v_exp_f32 per score).
// Round-7 lesson: K/V-REUSE-bound -> 4 q-tiles/wave, 50% occupancy (42us) is the optimum.
// Round-10 lesson: in-wave ILP doubling is neutral -> keep the simple single-chunk loop.
__global__ __launch_bounds__(512) void flash_kernel(const _Float16* __restrict__ qkvh,
    const _Float16* __restrict__ vt, float* __restrict__ attn){
  int h = blockIdx.y;
  int w = threadIdx.x >> 6, lane = threadIdx.x & 63;
  int q0 = blockIdx.x*64;
  int col = lane & 15, quad = lane >> 4;
  __shared__ float ll[8][4][16];
  __shared__ float lo[8][4][256];
  h4 qf[4];
  #pragma unroll
  for (int t=0;t<4;++t)
    qf[t] = *(const h4*)&qkvh[(size_t)(q0+t*16+col)*384 + h*16 + quad*4];
  f4t ov[4];
  float ls[4] = {0.f,0.f,0.f,0.f};
  #pragma unroll
  for (int t=0;t<4;++t){ ov[t][0]=0.f; ov[t][1]=0.f; ov[t][2]=0.f; ov[t][3]=0.f; }
  const _Float16* kbase = qkvh + 128 + h*16 + quad*4;
  const _Float16* vbase = vt + (size_t)(h*16+col)*4096 + quad*4;
  int jbeg = w*512, jend = jbeg + 512;
  h4 kf = *(const h4*)&kbase[(size_t)(jbeg+col)*384];
  h4 vf = *(const h4*)&vbase[jbeg];
  for (int j0=jbeg; j0<jend; j0+=16){
    h4 kc=kf, vc=vf;
    if (j0+16<jend){
      kf = *(const h4*)&kbase[(size_t)(j0+16+col)*384];
      vf = *(const h4*)&vbase[j0+16];
    }
    f4t s[4];
    #pragma unroll
    for (int t=0;t<4;++t){
      s[t][0]=0.f; s[t][1]=0.f; s[t][2]=0.f; s[t][3]=0.f;
      s[t] = __builtin_amdgcn_mfma_f32_16x16x16f16(kc, qf[t], s[t], 0,0,0);
    }
    #pragma unroll
    for (int t=0;t<4;++t){
      float p0=__builtin_amdgcn_exp2f(s[t][0]), p1=__builtin_amdgcn_exp2f(s[t][1]);
      float p2=__builtin_amdgcn_exp2f(s[t][2]), p3=__builtin_amdgcn_exp2f(s[t][3]);
      ls[t] += (p0+p1)+(p2+p3);
      fp16x2 plo = __builtin_amdgcn_cvt_pkrtz(p0,p1);
      fp16x2 phi = __builtin_amdgcn_cvt_pkrtz(p2,p3);
      h4 pf;
      pf[0]=(_Float16)plo[0]; pf[1]=(_Float16)plo[1];
      pf[2]=(_Float16)phi[0]; pf[3]=(_Float16)phi[1];
      ov[t] = __builtin_amdgcn_mfma_f32_16x16x16f16(vc, pf, ov[t], 0,0,0);
    }
  }
  #pragma unroll
  for (int t=0;t<4;++t){
    float l = ls[t];
    l += __shfl_xor(l,16);
    l += __shfl_xor(l,32);
    if (lane<16) ll[w][t][lane]=l;
    *(float4*)&lo[w][t][lane*4] = make_float4(ov[t][0],ov[t][1],ov[t][2],ov[t][3]);
  }
  __syncthreads();
  if (w < 4){
    int t = w;
    float l = 0.f;
    #pragma unroll
    for (int ww=0; ww<8; ++ww) l += ll[ww][t][col];
    float4 os = make_float4(0.f,0.f,0.f,0.f);
    #pragma unroll
    for (int ww=0; ww<8; ++ww){
      float4 owv = *(const float4*)&lo[ww][t][lane*4];
      os.x += owv.x; os.y += owv.y; os.z += owv.z; os.w += owv.w;
    }
    float inv = 1.0f/l;
    *(float4*)&attn[(size_t)(q0+t*16+col)*128 + h*16 + quad*4] =
        make_float4(os.x*inv, os.y*inv, os.z*inv, os.w*inv);
  }
}

// ---------------- agg1 (FUSED alpha+softmax+aggregation) ----------------
// Block per dst node. q_dst/t_dst staged in LDS once; per 32-edge chunk:
// per-(edge,head) thread computes the 128-dim logits (q.k_src + t.ea), then
// online-softmax (exact for degree<=32, which is ~all nodes), then aggregate.
// Removes the separate alpha kernel, the ALPHA buffer, and the 2nd full ea read.
// SEAGG lives in a fresh arena region (ws=256MiB), so no overlay race with QKVSG.
__global__ __launch_bounds__(256) void agg1_kernel(
    const ushort_t* __restrict__ lns, const float* __restrict__ ea,
    const ushort_t* __restrict__ qkvsg, const ushort_t* __restrict__ tbuf,
    const int* __restrict__ rows, const int* __restrict__ packe,
    const float* __restrict__ b_edge, const float* __restrict__ b_v,
    ushort_t* __restrict__ seagg, float* __restrict__ part)
{
  int n = blockIdx.x, tid = threadIdx.x;
  int d = tid & 127, h0 = tid >> 7;
  float sacc[4]={0.f,0.f,0.f,0.f}, eacc[4]={0.f,0.f,0.f,0.f}, wsacc[4]={0.f,0.f,0.f,0.f};
  float be[4];
  #pragma unroll
  for (int j=0;j<4;++j){
    int hd = (h0+2*j)*128 + d;
    be[j] = b_edge[hd] + b_v[hd];
  }
  int i0=rows[n], i1=rows[n+1];
  i0 = max(0,min(i0,NE)); i1 = max(i0,min(i1,NE));
  __shared__ ushort_t qs[1024], ts[1024];
  __shared__ float aa[32][8];
  __shared__ float wls[32][8];
  __shared__ float Msh[8], Rsh[8];
  __shared__ int es[32], srcs[32];
  *(uint2*)&qs[tid*4] = *(const uint2*)&qkvsg[(size_t)n*2048 + tid*4];
  *(uint2*)&ts[tid*4] = *(const uint2*)&tbuf[(size_t)n*1024 + tid*4];
  if (tid < 8) Msh[tid] = -1e30f;
  __syncthreads();
  for (int cs=i0; cs<i1; cs+=32){
    int cnt = min(32, i1-cs);
    if (tid < cnt){
      int v = packe[cs+tid];
      es[tid]   = v & 0xffff;
      srcs[tid] = (v>>16) & (NN-1);
    }
    __syncthreads();
    {
      int sl = tid>>3, hh = tid&7;
      if (sl < cnt){
        int e = es[sl], sr = srcs[sl];
        const ushort_t* kp = &qkvsg[(size_t)sr*2048 + 1024 + hh*128];
        const float*    ep = &ea[(size_t)e*128];
        const ushort_t* qp = &qs[hh*128];
        const ushort_t* tp = &ts[hh*128];
        float a0=0.f, a1=0.f;
        #pragma unroll
        for (int i=0;i<16;i+=2){
          a0 += bdot8(*(const uint4*)&qp[i*8],   *(const uint4*)&kp[i*8]);
          a1 += bdot8(*(const uint4*)&qp[i*8+8], *(const uint4*)&kp[i*8+8]);
          a0 += bfdot8v(*(const uint4*)&tp[i*8],   *(const float4*)&ep[i*8],   *(const float4*)&ep[i*8+4]);
          a1 += bfdot8v(*(const uint4*)&tp[i*8+8], *(const float4*)&ep[i*8+8], *(const float4*)&ep[i*8+12]);
        }
        aa[sl][hh] = 0.08838834764831845f*(a0+a1);
      }
    }
    __syncthreads();
    if (tid < 8){
      float cm = -1e30f;
      for (int j=0;j<cnt;++j) cm = fmaxf(cm, aa[j][tid]);
      float Mo = Msh[tid], Mn = fmaxf(Mo, cm);
      Rsh[tid] = __expf(Mo - Mn);          // 0 on first chunk (accs are 0)
      Msh[tid] = Mn;
    }
    __syncthreads();
    if (tid < cnt*8){
      int k=tid>>3, hh=tid&7;
      wls[k][hh] = __expf(aa[k][hh]-Msh[hh]);
    }
    __syncthreads();
    #pragma unroll
    for (int j=0;j<4;++j){
      float r = Rsh[h0+2*j];
      sacc[j]*=r; eacc[j]*=r; wsacc[j]*=r;
    }
    for (int k=0;k<cnt;++k){
      int e = es[k], sr = srcs[k];
      float lv = b2f(lns[(size_t)sr*128 + d]);
      float eav = ea[(size_t)e*128 + d];
      #pragma unroll
      for (int j=0;j<4;++j){
        float wv = wls[k][h0+2*j];
        sacc[j] += wv*lv;
        eacc[j] += wv*eav;
        wsacc[j] += wv;
      }
    }
    __syncthreads();
  }
  float partial = 0.f;
  #pragma unroll
  for (int j=0;j<4;++j){
    float inv = 1.0f/(wsacc[j]+1e-16f);
    int hd = (h0+2*j)*128 + d;
    seagg[(size_t)n*2048 + hd]        = f2b(sacc[j]*inv);
    seagg[(size_t)n*2048 + 1024 + hd] = f2b(eacc[j]*inv);
    partial += be[j]*wsacc[j]*inv;
  }
  __shared__ float pp[2][128];
  pp[h0][d] = partial;
  __syncthreads();
  if (tid<128) part[(size_t)n*128+tid] = (pp[0][tid]+pp[1][tid])*0.125f;
}

// ---------------- combine: skip-proj + corr sum + beta gate + residual + fused LN3 ----------------
__global__ __launch_bounds__(64) void combine_kernel(float* __restrict__ x2,
    const float* __restrict__ corrp, const float* __restrict__ part,
    ushort_t* __restrict__ lns, const float* __restrict__ w_s,
    const float* __restrict__ b_s, const float* __restrict__ x1,
    const float* __restrict__ w_beta,
    const float* __restrict__ n3g, const float* __restrict__ n3b)
{
  int n0 = blockIdx.x*2;
  int l = threadIdx.x;
  int d0 = 2*l, d1 = 2*l+1;
  __shared__ float sln[2][128];
  #pragma unroll
  for (int rr=0;rr<2;++rr){
    unsigned int u = *(const unsigned int*)&lns[(size_t)(n0+rr)*128 + d0];
    sln[rr][d0] = b2f((ushort_t)(u&0xffffu));
    sln[rr][d1] = b2f((ushort_t)(u>>16));
  }
  __syncthreads();
  float2 bsv = *(const float2*)&b_s[d0];
  float xr0[2], xr1[2];
  xr0[0]=bsv.x; xr0[1]=bsv.x; xr1[0]=bsv.y; xr1[1]=bsv.y;
  for (int i=0;i<128;++i){
    float2 wv = *(const float2*)&w_s[(size_t)i*128 + d0];
    #pragma unroll
    for (int rr=0;rr<2;++rr){
      float lv = sln[rr][i];
      xr0[rr] += lv*wv.x; xr1[rr] += lv*wv.y;
    }
  }
  float2 wb0 = *(const float2*)&w_beta[d0];
  float2 wb1 = *(const float2*)&w_beta[128+d0];
  float2 wb2 = *(const float2*)&w_beta[256+d0];
  float2 gv = *(const float2*)&n3g[d0];
  float2 bv = *(const float2*)&n3b[d0];
  #pragma unroll
  for (int rr=0;rr<2;++rr){
    size_t idx = (size_t)(n0+rr)*128 + d0;
    float2 pt = *(const float2*)&part[idx];
    float2 c0 = *(const float2*)&corrp[idx];
    float2 c1 = *(const float2*)&corrp[524288+idx];
    float2 c2 = *(const float2*)&corrp[1048576+idx];
    float2 c3 = *(const float2*)&corrp[1572864+idx];
    float o0 = pt.x+c0.x+c1.x+c2.x+c3.x;
    float o1 = pt.y+c0.y+c1.y+c2.y+c3.y;
    float xa = xr0[rr], xb = xr1[rr];
    float pr = o0*wb0.x + o1*wb0.y + xa*wb1.x + xb*wb1.y
             + (o0-xa)*wb2.x + (o1-xb)*wb2.y;
    pr += __shfl_xor(pr,1); pr += __shfl_xor(pr,2); pr += __shfl_xor(pr,4);
    pr += __shfl_xor(pr,8); pr += __shfl_xor(pr,16); pr += __shfl_xor(pr,32);
    float beta = 1.0f/(1.0f+__expf(-pr));
    float2 xv = *(const float2*)&x1[idx];
    float v0 = xv.x + beta*xa + (1.0f-beta)*o0;
    float v1 = xv.y + beta*xb + (1.0f-beta)*o1;
    *(float2*)&x2[idx] = make_float2(v0,v1);
    float s = v0+v1;
    s += __shfl_xor(s,1); s += __shfl_xor(s,2); s += __shfl_xor(s,4);
    s += __shfl_xor(s,8); s += __shfl_xor(s,16); s += __shfl_xor(s,32);
    float mean = s*(1.0f/128.0f);
    float e0=v0-mean, e1=v1-mean;
    float q = e0*e0+e1*e1;
    q += __shfl_xor(q,1); q += __shfl_xor(q,2); q += __shfl_xor(q,4);
    q += __shfl_xor(q,8); q += __shfl_xor(q,16); q += __shfl_xor(q,32);
    float rinv = rsqrtf(q*(1.0f/128.0f)+1e-5f);
    unsigned int pk2 = ((unsigned int)f2b(e1*rinv*gv.y+bv.y)<<16)
                     |  (unsigned int)f2b(e0*rinv*gv.x+bv.x);
    *(unsigned int*)&lns[idx] = pk2;
  }
}

// ---------------- gate (+f2 split-K reduce): one wave, 2 rows, shared wdyn loads ----------------
__global__ __launch_bounds__(64) void gate_kernel(const float* __restrict__ x3p,
    const float* __restrict__ b_f2, const float* __restrict__ x2,
    const float* __restrict__ x0, const ushort_t* __restrict__ wdyn,
    const float* __restrict__ b_dyn, float* __restrict__ out){
  int n0 = blockIdx.x*2;
  int l = threadIdx.x;
  int d0 = 2*l, d1 = 2*l+1;
  __shared__ float sA[2][128];
  __shared__ float sR[2][128];
  float a0[2], a1[2], r0[2], r1[2];
  float2 bb = *(const float2*)&b_f2[d0];
  #pragma unroll
  for (int rr=0;rr<2;++rr){
    size_t idx = (size_t)(n0+rr)*128 + d0;
    float2 p0v = *(const float2*)&x3p[idx];
    float2 p1v = *(const float2*)&x3p[524288+idx];
    float2 p2v = *(const float2*)&x3p[1048576+idx];
    float2 p3v = *(const float2*)&x3p[1572864+idx];
    float2 xv = *(const float2*)&x2[idx];
    float2 rv = *(const float2*)&x0[idx];
    a0[rr] = p0v.x+p1v.x+p2v.x+p3v.x+bb.x+xv.x;
    a1[rr] = p0v.y+p1v.y+p2v.y+p3v.y+bb.y+xv.y;
    r0[rr]=rv.x; r1[rr]=rv.y;
    sA[rr][d0]=a0[rr]; sA[rr][d1]=a1[rr];
    sR[rr][d0]=rv.x;  sR[rr][d1]=rv.y;
  }
  __syncthreads();
  float2 bd = *(const float2*)&b_dyn[d0];
  float g0[2], g1[2];
  g0[0]=bd.x; g0[1]=bd.x; g1[0]=bd.y; g1[1]=bd.y;
  for (int k=0;k<128;++k){
    unsigned int wv = *(const unsigned int*)&wdyn[(size_t)k*128 + d0];
    float w0=b2f((ushort_t)(wv&0xffffu)), w1=b2f((ushort_t)(wv>>16));
    #pragma unroll
    for (int rr=0;rr<2;++rr){
      float sk = sA[rr][k];
      g0[rr]+=sk*w0; g1[rr]+=sk*w1;
    }
  }
  for (int k=0;k<128;++k){
    unsigned int wv = *(const unsigned int*)&wdyn[(size_t)(128+k)*128 + d0];
    float w0=b2f((ushort_t)(wv&0xffffu)), w1=b2f((ushort_t)(wv>>16));
    #pragma unroll
    for (int rr=0;rr<2;++rr){
      float sk = sR[rr][k];
      g0[rr]+=sk*w0; g1[rr]+=sk*w1;
    }
  }
  #pragma unroll
  for (int rr=0;rr<2;++rr){
    size_t idx=(size_t)(n0+rr)*128 + d0;
    float gg0=1.0f/(1.0f+__expf(-g0[rr]));
    float gg1=1.0f/(1.0f+__expf(-g1[rr]));
    float v0=a0[rr]*gg0 + r0[rr]*(1.0f-gg0);
    float v1=a1[rr]*gg1 + r1[rr]*(1.0f-gg1);
    *(float2*)&out[idx]=make_float2(v0,v1);
  }
}

extern "C" void kernel_launch(void* const* d_in, const int* in_sizes, int n_in,
                              void* d_out, int out_size, void* d_ws, size_t ws_size,
                              hipStream_t stream) {
  const float* x    =(const float*)d_in[0];
  const int*   ei   =(const int*)  d_in[1];
  const float* eattr=(const float*)d_in[2];
  const float* n1g=(const float*)d_in[3], *n1b=(const float*)d_in[4];
  const float* n2g=(const float*)d_in[5], *n2b=(const float*)d_in[6];
  const float* n3g=(const float*)d_in[7], *n3b=(const float*)d_in[8];
  const float* w_qkv=(const float*)d_in[9],  *b_qkv=(const float*)d_in[10];
  const float* w_o  =(const float*)d_in[11], *b_o  =(const float*)d_in[12];
  const float* w_q  =(const float*)d_in[13], *b_q  =(const float*)d_in[14];
  const float* w_k  =(const float*)d_in[15], *b_k  =(const float*)d_in[16];
  const float* w_v  =(const float*)d_in[17], *b_v  =(const float*)d_in[18];
  const float* w_e  =(const float*)d_in[19], *b_e  =(const float*)d_in[20];
  const float* w_s  =(const float*)d_in[21], *b_s  =(const float*)d_in[22];
  const float* w_beta=(const float*)d_in[23];
  const float* w_f1 =(const float*)d_in[24], *b_f1=(const float*)d_in[25];
  const float* w_f2 =(const float*)d_in[26], *b_f2=(const float*)d_in[27];
  const float* w_dyn=(const float*)d_in[28], *b_dyn=(const float*)d_in[29];
  float* out=(float*)d_out;
  float* ws=(float*)d_ws;

  // ---- arena (float units). ws is 256 MiB (harness poison fill = 262144 KB),
  // so SEAGG gets a fresh region (no overlay with QKVSG -> fused agg1 is race-free).
  float* X1    = ws + 0;        // 524288
  float* X2    = ws + 524288;   // 524288 (ATTN alias; PACKE/BQKV overlay while X2 dead)
  ushort_t* LNS = (ushort_t*)(ws + 1048576); // bf16 4096x128 -> 1310720
  float* PART  = ws + 1310720;  // 524288 -> 1835008
  int*   ROWS  = (int*)(ws + 2359296);  // 4097 -> pad 2363456
  int*   CURS  = (int*)(ws + 2363456);  // -> 2367552
  int*   COUNT = (int*)(ws + 2433088);  // -> 2437184
  // PACKE: overlay X2 region (dead between mgemm(w_o) and combine)
  int*   PACKE = (int*)(ws + 589824);   // 65536 ints -> fu 655360
  // BQKV: 384 floats at X2 region tail; live only megawcvt -> qkv mgemm
  float* BQKV  = ws + 1048576 - 512;
  ushort_t* WBqkv = (ushort_t*)(ws + 2437184);
  ushort_t* WBo   = (ushort_t*)(ws + 2461760);
  ushort_t* WBG   = (ushort_t*)(ws + 2469952);
  ushort_t* WETB  = (ushort_t*)(ws + 2601024);
  ushort_t* WBf1  = (ushort_t*)(ws + 2666560);
  ushort_t* WBf2  = (ushort_t*)(ws + 2797632);
  ushort_t* WCAT  = (ushort_t*)(ws + 2928704);
  float* BCAT  = ws + 3059776;
  ushort_t* WDYN = (ushort_t*)(ws + 3061824);
  // BIG overlay at 3078208
  _Float16* QKVH  = (_Float16*)(ws + 3078208);
  _Float16* VT    = (_Float16*)(ws + 3864640);
  ushort_t* QKVSG = (ushort_t*)(ws + 3078208); // live LN2..agg1
  ushort_t* MID   = (ushort_t*)(ws + 3078208); // overlays QKVSG post-agg1 (FFN)
  ushort_t* T     = (ushort_t*)(ws + 7272512); // live T-GEMM..agg1
  float* CORRP = ws + 7272512;  // overlays T post-agg1 (corr GEMM)
  float* X3P   = ws + 7272512;  // overlays CORRP (FFN)
  // SEAGG: fresh region past old arena peak (9369664); 4M fu -> ends 13631488 (54.5 MiB)
  ushort_t* SEAGG = (ushort_t*)(ws + 9437184);
  float* ATTN  = X2;

  megawcvt_kernel<<<1256,256,0,stream>>>(w_qkv,w_o,w_q,w_k,w_v,w_e,w_f1,w_f2,
                                         b_q,b_k,w_dyn,b_qkv,
                                         WBqkv,WBo,WBG,WETB,WBf1,WBf2,WCAT,BCAT,WDYN,COUNT,BQKV);

  // ---- block 1: LN1 (+edge count) + dense MHA (V^T + CSR scan fused into QKV GEMM) ----
  ln_kernel<<<1024,256,0,stream>>>(x, n1g, n1b, LNS, ei, COUNT, nullptr,nullptr);
  mgemm_kernel<1,2,1><<<dim3(7,32,1),256,0,stream>>>(LNS,128,0, WBqkv,128,0, BQKV, nullptr, QKVH,384,0, 128, 0, VT, COUNT, ROWS, CURS);
  flash_kernel<<<dim3(64,8),512,0,stream>>>(QKVH, VT, ATTN);
  mgemm_kernel<0,0,0><<<dim3(2,32,1),256,0,stream>>>(ATTN,128,0, WBo,128,0, b_o, x, X1,128,0, 128, 0, nullptr, nullptr,nullptr,nullptr);

  // ---- block 2: LN2 (+CSR scatter -> PACKE) + TransformerConv (alpha fused into agg1) ----
  ln_kernel<<<1280,256,0,stream>>>(X1, n2g, n2b, LNS, ei, nullptr, CURS, PACKE);
  mgemm_kernel<1,1,0><<<dim3(32,32,1),256,0,stream>>>(LNS,128,0, WBG,128,0, BCAT, nullptr, QKVSG,2048,0, 128, 0, nullptr, nullptr,nullptr,nullptr);
  mgemm_kernel<1,1,0><<<dim3(2,32,8),256,0,stream>>>(QKVSG,2048,128, WETB,128,16384, nullptr, nullptr, T,1024,128, 128, 0, nullptr, nullptr,nullptr,nullptr);
  agg1_kernel<<<NN,256,0,stream>>>(LNS, eattr, QKVSG, T, ROWS, PACKE, b_e, b_v, SEAGG, PART);
  mgemm_kernel<1,0,0><<<dim3(2,32,4),256,0,stream>>>(SEAGG,2048,512, WCAT,2048,512, nullptr, nullptr, CORRP,128,524288, 512, 0, nullptr, nullptr,nullptr,nullptr);
  combine_kernel<<<2048,64,0,stream>>>(X2, CORRP, PART, LNS, w_s, b_s, X1, w_beta, n3g, n3b);

  // ---- block 3: FFN (LN3 fused into combine -> LNS) ----
  mgemm_kernel<1,1,0><<<dim3(32,32,1),256,0,stream>>>(LNS,128,0, WBf1,128,0, b_f1, nullptr, MID,2048,0, 128, 1, nullptr, nullptr,nullptr,nullptr);
  mgemm_kernel<1,0,0><<<dim3(2,32,4),256,0,stream>>>(MID,2048,512, WBf2,2048,512, nullptr, nullptr, X3P,128,524288, 512, 0, nullptr, nullptr,nullptr,nullptr);

  // ---- block 4: FFN reduce + gated fusion ----
  gate_kernel<<<2048,64,0,stream>>>(X3P, b_f2, X2, x, WDYN, b_dyn, out);
}

// Round 13
// 359.053 us; speedup vs baseline: 1.0839x; 1.0839x over previous
//
#include <hip/hip_runtime.h>
#include <math.h>
#include <cstddef>

#define NN 4096
#define DIMC 128
#define NHEADS 8
#define NE 65536

typedef unsigned short ushort_t;
typedef short bs8 __attribute__((ext_vector_type(8)));
typedef float f32x16 __attribute__((ext_vector_type(16)));
typedef _Float16 h4 __attribute__((ext_vector_type(4)));
typedef __fp16 fp16x2 __attribute__((ext_vector_type(2)));
typedef float f4t __attribute__((ext_vector_type(4)));

__device__ __forceinline__ float b2f(ushort_t u){
  unsigned int i = ((unsigned int)u)<<16; float f;
  __builtin_memcpy(&f,&i,4); return f;
}
__device__ __forceinline__ ushort_t f2b(float f){
  unsigned int x; __builtin_memcpy(&x,&f,4);
  unsigned int r = x + 0x7fffu + ((x>>16)&1u);
  return (ushort_t)(r>>16);
}
__device__ __forceinline__ float bdot8(uint4 a, uint4 b){
  unsigned int ua[4]={a.x,a.y,a.z,a.w}, ub[4]={b.x,b.y,b.z,b.w};
  float s=0.f;
  #pragma unroll
  for (int i=0;i<4;++i){
    unsigned int al=ua[i]<<16, ah=ua[i]&0xffff0000u, bl=ub[i]<<16, bh=ub[i]&0xffff0000u;
    float fa,fb,fc,fd;
    __builtin_memcpy(&fa,&al,4); __builtin_memcpy(&fb,&ah,4);
    __builtin_memcpy(&fc,&bl,4); __builtin_memcpy(&fd,&bh,4);
    s += fa*fc + fb*fd;
  }
  return s;
}
// bf16x8 (uint4) dot fp32x8 (two float4s)
__device__ __forceinline__ float bfdot8v(uint4 a, float4 e0, float4 e1){
  unsigned int ua[4]={a.x,a.y,a.z,a.w};
  float eb[8]={e0.x,e0.y,e0.z,e0.w,e1.x,e1.y,e1.z,e1.w};
  float s=0.f;
  #pragma unroll
  for (int i=0;i<4;++i){
    unsigned int al=ua[i]<<16, ah=ua[i]&0xffff0000u;
    float fa,fb;
    __builtin_memcpy(&fa,&al,4); __builtin_memcpy(&fb,&ah,4);
    s += fa*eb[2*i] + fb*eb[2*i+1];
  }
  return s;
}

// ---------------- scan (256-thread version, runs as a spare block in qkv GEMM) ----------------
__device__ void scan256(const int* __restrict__ cnt, int* __restrict__ rows,
                        int* __restrict__ cursor){
  __shared__ int sums[256];
  int t = threadIdx.x;
  int base = t*16;
  int c[16]; int local=0;
  #pragma unroll
  for (int i=0;i<16;++i){ c[i]=cnt[base+i]; local+=c[i]; }
  sums[t]=local; __syncthreads();
  for (int off=1; off<256; off<<=1){
    int v = (t>=off)? sums[t-off] : 0; __syncthreads();
    sums[t]+=v; __syncthreads();
  }
  int r = sums[t]-local;
  #pragma unroll
  for (int i=0;i<16;++i){ rows[base+i]=r; cursor[base+i]=r; r+=c[i]; }
  if (t==255) rows[4096]=r;
}

// ---------------- LayerNorm: wave-per-row + fused count (ln1) / scatter (ln2) ----------------
// blocks [0,1024): LN of 4 rows each; if cnt!=null also one edge-count atomic per thread.
// blocks [1024,1280) (ln2 only): CSR scatter of 256 edges each (needs cursor from scan).
__global__ __launch_bounds__(256) void ln_kernel(const float* __restrict__ x,
    const float* __restrict__ g, const float* __restrict__ b, ushort_t* __restrict__ y,
    const int* __restrict__ ei, int* __restrict__ cnt,
    int* __restrict__ cursor, int* __restrict__ csr,
    int* __restrict__ pack, int* __restrict__ packe){
  int bb = blockIdx.x;
  if (bb >= 1024){
    int e = (bb-1024)*256 + threadIdx.x;
    int src = ei[e] & (NN-1), dst = ei[NE+e] & (NN-1);
    int pos = atomicAdd(&cursor[dst],1);
    if (pos >= 0 && pos < NE){
      csr[pos]=e; pack[pos]=src|(dst<<12); packe[pos]=e|(src<<16);
    }
    return;
  }
  int n = bb*4 + (threadIdx.x>>6);
  int l = threadIdx.x & 63;
  int d0 = 2*l;
  float2 v = *(const float2*)&x[(size_t)n*DIMC + d0];
  float s = v.x+v.y;
  s += __shfl_xor(s,1); s += __shfl_xor(s,2); s += __shfl_xor(s,4);
  s += __shfl_xor(s,8); s += __shfl_xor(s,16); s += __shfl_xor(s,32);
  float mean = s*(1.0f/128.0f);
  float c0=v.x-mean, c1=v.y-mean;
  float q=c0*c0+c1*c1;
  q += __shfl_xor(q,1); q += __shfl_xor(q,2); q += __shfl_xor(q,4);
  q += __shfl_xor(q,8); q += __shfl_xor(q,16); q += __shfl_xor(q,32);
  float rinv = rsqrtf(q*(1.0f/128.0f)+1e-5f);
  float2 gv = *(const float2*)&g[d0];
  float2 bv = *(const float2*)&b[d0];
  unsigned int pk = ((unsigned int)f2b(c1*rinv*gv.y+bv.y)<<16) | (unsigned int)f2b(c0*rinv*gv.x+bv.x);
  *(unsigned int*)&y[(size_t)n*DIMC + d0] = pk;
  if (cnt){
    int gid = bb*256 + threadIdx.x;
    if (gid < NE) atomicAdd(&cnt[ei[NE+gid] & (NN-1)],1);
  }
}

// ---------------- one-shot weight convert: LDS-tiled coalesced transposes ----------------
#define QSCALE 0.36067376022224085f
__global__ __launch_bounds__(256) void megawcvt_kernel(
    const float* __restrict__ w_qkv, const float* __restrict__ w_o,
    const float* __restrict__ w_q, const float* __restrict__ w_k,
    const float* __restrict__ w_v, const float* __restrict__ w_e,
    const float* __restrict__ w_f1, const float* __restrict__ w_f2,
    const float* __restrict__ bq, const float* __restrict__ bk,
    const float* __restrict__ w_dyn, const float* __restrict__ b_qkv,
    ushort_t* __restrict__ WBqkv, ushort_t* __restrict__ WBo, ushort_t* __restrict__ WBG,
    ushort_t* __restrict__ WETB, ushort_t* __restrict__ WBf1, ushort_t* __restrict__ WBf2,
    ushort_t* __restrict__ WCAT, float* __restrict__ BCAT, ushort_t* __restrict__ WDYN,
    int* __restrict__ COUNT, float* __restrict__ BQKV)
{
  int b = blockIdx.x, tid = threadIdx.x;
  if (b < 1216){
    const float* src; int srcStride; ushort_t* dst; int dstStride;
    int n0, k0; float scale = 1.0f;
    if (b < 48){ int nt=b>>2, kt=b&3; src=w_qkv; srcStride=384; dst=WBqkv; dstStride=128;
      n0=nt*32; k0=kt*32; if (nt<4) scale=QSCALE; }
    else if (b < 64){ int l=b-48, nt=l>>2, kt=l&3; src=w_o; srcStride=128; dst=WBo; dstStride=128; n0=nt*32; k0=kt*32; }
    else if (b < 192){ int l=b-64, nt=l>>2, kt=l&3; src=w_q; srcStride=1024; dst=WBG; dstStride=128; n0=nt*32; k0=kt*32; }
    else if (b < 320){ int l=b-192, nt=l>>2, kt=l&3; src=w_k; srcStride=1024; dst=WBG+1024*128; dstStride=128; n0=nt*32; k0=kt*32; }
    else if (b < 448){ int l=b-320, nt=l>>2, kt=l&3; src=w_e; srcStride=1024; dst=WETB; dstStride=128; n0=nt*32; k0=kt*32; }
    else if (b < 704){ int l=b-448, nt=l>>2, kt=l&3; src=w_f1; srcStride=2048; dst=WBf1; dstStride=128; n0=nt*32; k0=kt*32; }
    else if (b < 960){ int l=b-704, nt=l>>6, kt=l&63; src=w_f2; srcStride=128; dst=WBf2; dstStride=2048; n0=nt*32; k0=kt*32; }
    else if (b < 1088){ int l=b-960, h=l>>4, tt=l&15, nt=tt>>2, kt=tt&3;
      src=w_v+h*128; srcStride=1024; dst=WCAT+h*128; dstStride=2048; n0=nt*32; k0=kt*32; scale=0.125f; }
    else { int l=b-1088, h=l>>4, tt=l&15, nt=tt>>2, kt=tt&3;
      src=w_e+h*128; srcStride=1024; dst=WCAT+1024+h*128; dstStride=2048; n0=nt*32; k0=kt*32; scale=0.125f; }
    __shared__ float lt[32*33];
    int rr = tid>>3, cg = (tid&7)*4;
    float4 v = *(const float4*)&src[(size_t)(k0+rr)*srcStride + n0 + cg];
    lt[rr*33+cg]=v.x; lt[rr*33+cg+1]=v.y; lt[rr*33+cg+2]=v.z; lt[rr*33+cg+3]=v.w;
    __syncthreads();
    ushort_t o[4] __attribute__((aligned(8)));
    #pragma unroll
    for (int j=0;j<4;++j) o[j] = f2b(lt[(cg+j)*33 + rr]*scale);
    *(ushort4*)&dst[(size_t)(n0+rr)*dstStride + k0 + cg] = *(ushort4*)o;
  } else {
    for (int id=(b-1216)*256+tid; id<39296; id += 40*256){
      if (id < 2048) BCAT[id] = (id<1024)? bq[id] : bk[id-1024];
      else if (id < 34816){ int l=id-2048; WDYN[l]=f2b(w_dyn[l]); }
      else if (id < 38912) COUNT[id-34816]=0;
      else { int l=id-38912; BQKV[l]=b_qkv[l]*((l<128)?QSCALE:1.0f); }
    }
  }
}

// ---------------- MFMA GEMM (fused V^T side-store; optional fused scan block) ----------------
template<int A_BF16, int C_MODE, int FUSE_SCAN>
__global__ __launch_bounds__(256) void mgemm_kernel(
    const void* __restrict__ Av, int lda, int strideA,
    const ushort_t* __restrict__ BT, int ldbt, int strideB,
    const float* __restrict__ bias,
    const float* __restrict__ res,
    void* __restrict__ Cv, int ldc, int strideC,
    int K, int act_gelu, _Float16* __restrict__ vtout,
    const int* __restrict__ scnt, int* __restrict__ srows, int* __restrict__ scur)
{
  if (FUSE_SCAN){
    if (blockIdx.x == gridDim.x-1){
      if (blockIdx.y==0 && blockIdx.z==0) scan256(scnt, srows, scur);
      return;
    }
  }
  int z = blockIdx.z;
  int m0 = blockIdx.y*128, n0 = blockIdx.x*64;
  int tid = threadIdx.x;
  int w = tid>>6, lane = tid&63;
  int kg = lane>>5;
  int ml = w*32 + (lane&31);
  int sw = (ml>>1)&3;
  __shared__ ushort_t As[128*32];
  const ushort_t* BTz = BT + (size_t)z*strideB;
  f32x16 acc[2];
  #pragma unroll
  for (int i=0;i<16;++i){ acc[0][i]=0.f; acc[1][i]=0.f; }

  for (int k0=0; k0<K; k0+=32){
    {
      int rr = tid>>1, kc = (tid&1)*16;
      int rowg = m0 + rr;
      ushort_t tmp[16] __attribute__((aligned(16)));
      if (A_BF16){
        const ushort_t* A = (const ushort_t*)Av + (size_t)z*strideA;
        uint4 u0 = *(const uint4*)&A[(size_t)rowg*lda + k0 + kc];
        uint4 u1 = *(const uint4*)&A[(size_t)rowg*lda + k0 + kc + 8];
        __builtin_memcpy(tmp, &u0, 16); __builtin_memcpy(tmp+8, &u1, 16);
      } else {
        const float* A = (const float*)Av + (size_t)z*strideA;
        const float* p = &A[(size_t)rowg*lda + k0 + kc];
        float4 f0=*(const float4*)p, f1=*(const float4*)(p+4);
        float4 f2v=*(const float4*)(p+8), f3=*(const float4*)(p+12);
        tmp[0]=f2b(f0.x); tmp[1]=f2b(f0.y); tmp[2]=f2b(f0.z); tmp[3]=f2b(f0.w);
        tmp[4]=f2b(f1.x); tmp[5]=f2b(f1.y); tmp[6]=f2b(f1.z); tmp[7]=f2b(f1.w);
        tmp[8]=f2b(f2v.x); tmp[9]=f2b(f2v.y); tmp[10]=f2b(f2v.z); tmp[11]=f2b(f2v.w);
        tmp[12]=f2b(f3.x); tmp[13]=f2b(f3.y); tmp[14]=f2b(f3.z); tmp[15]=f2b(f3.w);
      }
      int swr = (rr>>1)&3, c0 = kc>>3;
      *(uint4*)&As[rr*32 + (((c0  )^swr)*8)] = *(const uint4*)tmp;
      *(uint4*)&As[rr*32 + (((c0+1)^swr)*8)] = *(const uint4*)(tmp+8);
    }
    __syncthreads();
    bs8 a0 = *(bs8*)&As[ml*32 + (((0*2+kg)^sw)*8)];
    bs8 a1 = *(bs8*)&As[ml*32 + (((1*2+kg)^sw)*8)];
    #pragma unroll
    for (int nt=0; nt<2; ++nt){
      const ushort_t* bp = &BTz[(size_t)(n0 + nt*32 + (lane&31))*ldbt + k0 + kg*8];
      uint4 rb0 = *(const uint4*)bp;
      uint4 rb1 = *(const uint4*)(bp + 16);
      bs8 b0, b1;
      __builtin_memcpy(&b0, &rb0, 16); __builtin_memcpy(&b1, &rb1, 16);
      acc[nt] = __builtin_amdgcn_mfma_f32_32x32x16_bf16(a0, b0, acc[nt], 0,0,0);
      acc[nt] = __builtin_amdgcn_mfma_f32_32x32x16_bf16(a1, b1, acc[nt], 0,0,0);
    }
    __syncthreads();
  }
  #pragma unroll
  for (int nt=0; nt<2; ++nt){
    int col = n0 + nt*32 + (lane&31);
    float bv = bias ? bias[col] : 0.f;
    #pragma unroll
    for (int r=0; r<16; ++r){
      int rowl = (r&3) + 8*(r>>2) + 4*kg;
      int row = m0 + w*32 + rowl;
      float v = acc[nt][r] + bv;
      if (act_gelu) v = 0.5f*v*(1.0f+erff(v*0.70710678118654752f));
      if (res) v += res[(size_t)row*ldc + col];
      size_t idx = (size_t)z*strideC + (size_t)row*ldc + col;
      if (C_MODE==1)      ((ushort_t*)Cv)[idx] = f2b(v);
      else if (C_MODE==2){
        _Float16 hv = (_Float16)v;
        ((_Float16*)Cv)[idx] = hv;
        if (vtout && col>=256) vtout[(size_t)(col-256)*4096 + row] = hv;
      }
      else                ((float*)Cv)[idx]    = v;
    }
  }
}

// ---------------- Flash MHA: MFMA, m=0, 4 q-tiles per wave, K-split x8 ----------------
// Q pre-scaled by 0.25*log2(e), so p = 2^s (single v_exp_f32 per score).
// Round-7 lesson: K/V-REUSE-bound -> 4 q-tiles/wave, 50% occupancy (42us) is the optimum.
// Round-10 lesson: in-wave ILP doubling is neutral -> keep the simple single-chunk loop.
__global__ __launch_bounds__(512) void flash_kernel(const _Float16* __restrict__ qkvh,
    const _Float16* __restrict__ vt, float* __restrict__ attn){
  int h = blockIdx.y;
  int w = threadIdx.x >> 6, lane = threadIdx.x & 63;
  int q0 = blockIdx.x*64;
  int col = lane & 15, quad = lane >> 4;
  __shared__ float ll[8][4][16];
  __shared__ float lo[8][4][256];
  h4 qf[4];
  #pragma unroll
  for (int t=0;t<4;++t)
    qf[t] = *(const h4*)&qkvh[(size_t)(q0+t*16+col)*384 + h*16 + quad*4];
  f4t ov[4];
  float ls[4] = {0.f,0.f,0.f,0.f};
  #pragma unroll
  for (int t=0;t<4;++t){ ov[t][0]=0.f; ov[t][1]=0.f; ov[t][2]=0.f; ov[t][3]=0.f; }
  const _Float16* kbase = qkvh + 128 + h*16 + quad*4;
  const _Float16* vbase = vt + (size_t)(h*16+col)*4096 + quad*4;
  int jbeg = w*512, jend = jbeg + 512;
  h4 kf = *(const h4*)&kbase[(size_t)(jbeg+col)*384];
  h4 vf = *(const h4*)&vbase[jbeg];
  for (int j0=jbeg; j0<jend; j0+=16){
    h4 kc=kf, vc=vf;
    if (j0+16<jend){
      kf = *(const h4*)&kbase[(size_t)(j0+16+col)*384];
      vf = *(const h4*)&vbase[j0+16];
    }
    f4t s[4];
    #pragma unroll
    for (int t=0;t<4;++t){
      s[t][0]=0.f; s[t][1]=0.f; s[t][2]=0.f; s[t][3]=0.f;
      s[t] = __builtin_amdgcn_mfma_f32_16x16x16f16(kc, qf[t], s[t], 0,0,0);
    }
    #pragma unroll
    for (int t=0;t<4;++t){
      float p0=__builtin_amdgcn_exp2f(s[t][0]), p1=__builtin_amdgcn_exp2f(s[t][1]);
      float p2=__builtin_amdgcn_exp2f(s[t][2]), p3=__builtin_amdgcn_exp2f(s[t][3]);
      ls[t] += (p0+p1)+(p2+p3);
      fp16x2 plo = __builtin_amdgcn_cvt_pkrtz(p0,p1);
      fp16x2 phi = __builtin_amdgcn_cvt_pkrtz(p2,p3);
      h4 pf;
      pf[0]=(_Float16)plo[0]; pf[1]=(_Float16)plo[1];
      pf[2]=(_Float16)phi[0]; pf[3]=(_Float16)phi[1];
      ov[t] = __builtin_amdgcn_mfma_f32_16x16x16f16(vc, pf, ov[t], 0,0,0);
    }
  }
  #pragma unroll
  for (int t=0;t<4;++t){
    float l = ls[t];
    l += __shfl_xor(l,16);
    l += __shfl_xor(l,32);
    if (lane<16) ll[w][t][lane]=l;
    *(float4*)&lo[w][t][lane*4] = make_float4(ov[t][0],ov[t][1],ov[t][2],ov[t][3]);
  }
  __syncthreads();
  if (w < 4){
    int t = w;
    float l = 0.f;
    #pragma unroll
    for (int ww=0; ww<8; ++ww) l += ll[ww][t][col];
    float4 os = make_float4(0.f,0.f,0.f,0.f);
    #pragma unroll
    for (int ww=0; ww<8; ++ww){
      float4 owv = *(const float4*)&lo[ww][t][lane*4];
      os.x += owv.x; os.y += owv.y; os.z += owv.z; os.w += owv.w;
    }
    float inv = 1.0f/l;
    *(float4*)&attn[(size_t)(q0+t*16+col)*128 + h*16 + quad*4] =
        make_float4(os.x*inv, os.y*inv, os.z*inv, os.w*inv);
  }
}

// ---------------- alpha: 2 edges per wave, all 8 heads, CSR-ordered ----------------
__global__ __launch_bounds__(256) void alpha_kernel(
    const float* __restrict__ ea, const ushort_t* __restrict__ qkvsg,
    const ushort_t* __restrict__ t, const int* __restrict__ csr,
    const int* __restrict__ pack, float* __restrict__ alpha){
  int tid = threadIdx.x;
  int w = tid>>6, lane = tid&63;
  int h = lane>>3, li = lane&7;
  int off = h*128 + li*16;
  int ibase = blockIdx.x*8 + w*2;
  int2 pk = *(const int2*)&pack[ibase];
  int2 ec = *(const int2*)&csr[ibase];
  int e0 = ec.x & (NE-1), e1 = ec.y & (NE-1);
  int s0 = pk.x & 4095, d0 = (pk.x>>12) & 4095;
  int s1 = pk.y & 4095, d1 = (pk.y>>12) & 4095;

  const ushort_t* q0p = &qkvsg[(size_t)d0*2048 + off];
  const ushort_t* k0p = &qkvsg[(size_t)s0*2048 + 1024 + off];
  const ushort_t* t0p = &t[(size_t)d0*1024 + off];
  const float*    e0p = &ea[(size_t)e0*128 + li*16];
  const ushort_t* q1p = &qkvsg[(size_t)d1*2048 + off];
  const ushort_t* k1p = &qkvsg[(size_t)s1*2048 + 1024 + off];
  const ushort_t* t1p = &t[(size_t)d1*1024 + off];
  const float*    e1p = &ea[(size_t)e1*128 + li*16];

  uint4 q00=*(const uint4*)q0p,      q01=*(const uint4*)(q0p+8);
  uint4 k00=*(const uint4*)k0p,      k01=*(const uint4*)(k0p+8);
  uint4 t00=*(const uint4*)t0p,      t01=*(const uint4*)(t0p+8);
  float4 ea00=*(const float4*)e0p,   ea01=*(const float4*)(e0p+4);
  float4 ea02=*(const float4*)(e0p+8), ea03=*(const float4*)(e0p+12);
  uint4 q10=*(const uint4*)q1p,      q11=*(const uint4*)(q1p+8);
  uint4 k10=*(const uint4*)k1p,      k11=*(const uint4*)(k1p+8);
  uint4 t10=*(const uint4*)t1p,      t11=*(const uint4*)(t1p+8);
  float4 ea10=*(const float4*)e1p,   ea11=*(const float4*)(e1p+4);
  float4 ea12=*(const float4*)(e1p+8), ea13=*(const float4*)(e1p+12);

  float p0 = bdot8(q00,k00) + bdot8(q01,k01)
           + bfdot8v(t00,ea00,ea01) + bfdot8v(t01,ea02,ea03);
  float p1 = bdot8(q10,k10) + bdot8(q11,k11)
           + bfdot8v(t10,ea10,ea11) + bfdot8v(t11,ea12,ea13);
  p0 += __shfl_xor(p0,1); p0 += __shfl_xor(p0,2); p0 += __shfl_xor(p0,4);
  p1 += __shfl_xor(p1,1); p1 += __shfl_xor(p1,2); p1 += __shfl_xor(p1,4);
  if (li==0){
    alpha[(size_t)ibase*8 + h]     = 0.08838834764831845f*p0;
    alpha[(size_t)(ibase+1)*8 + h] = 0.08838834764831845f*p1;
  }
}

// ---------------- agg1: softmax + LN2/ea aggregation -> SEAGG + PART ----------------
// packe[i] = e | (src<<16) -> single sequential index stream.
// Round-11: parallel max phase (1 load/edge block-wide vs 256x serial re-reads),
// chunk 32 (avg degree 16 -> almost always a single chunk, halving barriers).
__global__ __launch_bounds__(256) void agg1_kernel(
    const ushort_t* __restrict__ lns, const float* __restrict__ ea,
    const float* __restrict__ abuf, const int* __restrict__ rows,
    const int* __restrict__ packe,
    const float* __restrict__ b_edge, const float* __restrict__ b_v,
    ushort_t* __restrict__ seagg, float* __restrict__ part)
{
  int n = blockIdx.x, tid = threadIdx.x;
  int d = tid & 127, h0 = tid >> 7;
  float sacc[4]={0.f,0.f,0.f,0.f}, eacc[4]={0.f,0.f,0.f,0.f}, wsacc[4]={0.f,0.f,0.f,0.f};
  float be[4];
  #pragma unroll
  for (int j=0;j<4;++j){
    int hd = (h0+2*j)*128 + d;
    be[j] = b_edge[hd] + b_v[hd];
  }
  int i0=rows[n], i1=rows[n+1];
  i0 = max(0,min(i0,NE)); i1 = max(i0,min(i1,NE));
  __shared__ float smh[8];
  __shared__ float rmx[32][8];
  __shared__ float wls[32][8];
  __shared__ int es[32], srcs[32];
  {
    int hh = tid&7, sl = tid>>3;   // 32 slots x 8 heads: one abuf load per (edge,head)
    float m = -1e30f;
    for (int i=i0+sl; i<i1; i+=32)
      m = fmaxf(m, abuf[(size_t)i*8 + hh]);
    rmx[sl][hh] = m;
  }
  __syncthreads();
  if (tid < 8){
    float m = -1e30f;
    #pragma unroll
    for (int j=0;j<32;++j) m = fmaxf(m, rmx[j][tid]);
    smh[tid] = m;
  }
  __syncthreads();
  for (int cs=i0; cs<i1; cs+=32){
    int cnt = min(32, i1-cs);
    if (tid < cnt){
      int v = packe[cs+tid];
      es[tid]   = v & 0xffff;
      srcs[tid] = (v>>16) & (NN-1);
    }
    if (tid < cnt*8){
      int k=tid>>3, hh=tid&7;
      wls[k][hh] = __expf(abuf[(size_t)(cs+k)*8+hh]-smh[hh]);
    }
    __syncthreads();
    for (int k=0;k<cnt;++k){
      int e = es[k], sr = srcs[k];
      float lv = b2f(lns[(size_t)sr*128 + d]);
      float eav = ea[(size_t)e*128 + d];
      #pragma unroll
      for (int j=0;j<4;++j){
        float wv = wls[k][h0+2*j];
        sacc[j] += wv*lv;
        eacc[j] += wv*eav;
        wsacc[j] += wv;
      }
    }
    __syncthreads();
  }
  float partial = 0.f;
  #pragma unroll
  for (int j=0;j<4;++j){
    float inv = 1.0f/(wsacc[j]+1e-16f);
    int hd = (h0+2*j)*128 + d;
    seagg[(size_t)n*2048 + hd]        = f2b(sacc[j]*inv);
    seagg[(size_t)n*2048 + 1024 + hd] = f2b(eacc[j]*inv);
    partial += be[j]*wsacc[j]*inv;
  }
  __shared__ float pp[2][128];
  pp[h0][d] = partial;
  __syncthreads();
  if (tid<128) part[(size_t)n*128+tid] = (pp[0][tid]+pp[1][tid])*0.125f;
}

// ---------------- combine: skip-proj + corr sum + beta gate + residual + fused LN3 ----------------
__global__ __launch_bounds__(64) void combine_kernel(float* __restrict__ x2,
    const float* __restrict__ corrp, const float* __restrict__ part,
    ushort_t* __restrict__ lns, const float* __restrict__ w_s,
    const float* __restrict__ b_s, const float* __restrict__ x1,
    const float* __restrict__ w_beta,
    const float* __restrict__ n3g, const float* __restrict__ n3b)
{
  int n0 = blockIdx.x*2;
  int l = threadIdx.x;
  int d0 = 2*l, d1 = 2*l+1;
  __shared__ float sln[2][128];
  #pragma unroll
  for (int rr=0;rr<2;++rr){
    unsigned int u = *(const unsigned int*)&lns[(size_t)(n0+rr)*128 + d0];
    sln[rr][d0] = b2f((ushort_t)(u&0xffffu));
    sln[rr][d1] = b2f((ushort_t)(u>>16));
  }
  __syncthreads();
  float2 bsv = *(const float2*)&b_s[d0];
  float xr0[2], xr1[2];
  xr0[0]=bsv.x; xr0[1]=bsv.x; xr1[0]=bsv.y; xr1[1]=bsv.y;
  for (int i=0;i<128;++i){
    float2 wv = *(const float2*)&w_s[(size_t)i*128 + d0];
    #pragma unroll
    for (int rr=0;rr<2;++rr){
      float lv = sln[rr][i];
      xr0[rr] += lv*wv.x; xr1[rr] += lv*wv.y;
    }
  }
  float2 wb0 = *(const float2*)&w_beta[d0];
  float2 wb1 = *(const float2*)&w_beta[128+d0];
  float2 wb2 = *(const float2*)&w_beta[256+d0];
  float2 gv = *(const float2*)&n3g[d0];
  float2 bv = *(const float2*)&n3b[d0];
  #pragma unroll
  for (int rr=0;rr<2;++rr){
    size_t idx = (size_t)(n0+rr)*128 + d0;
    float2 pt = *(const float2*)&part[idx];
    float2 c0 = *(const float2*)&corrp[idx];
    float2 c1 = *(const float2*)&corrp[524288+idx];
    float2 c2 = *(const float2*)&corrp[1048576+idx];
    float2 c3 = *(const float2*)&corrp[1572864+idx];
    float o0 = pt.x+c0.x+c1.x+c2.x+c3.x;
    float o1 = pt.y+c0.y+c1.y+c2.y+c3.y;
    float xa = xr0[rr], xb = xr1[rr];
    float pr = o0*wb0.x + o1*wb0.y + xa*wb1.x + xb*wb1.y
             + (o0-xa)*wb2.x + (o1-xb)*wb2.y;
    pr += __shfl_xor(pr,1); pr += __shfl_xor(pr,2); pr += __shfl_xor(pr,4);
    pr += __shfl_xor(pr,8); pr += __shfl_xor(pr,16); pr += __shfl_xor(pr,32);
    float beta = 1.0f/(1.0f+__expf(-pr));
    float2 xv = *(const float2*)&x1[idx];
    float v0 = xv.x + beta*xa + (1.0f-beta)*o0;
    float v1 = xv.y + beta*xb + (1.0f-beta)*o1;
    *(float2*)&x2[idx] = make_float2(v0,v1);
    float s = v0+v1;
    s += __shfl_xor(s,1); s += __shfl_xor(s,2); s += __shfl_xor(s,4);
    s += __shfl_xor(s,8); s += __shfl_xor(s,16); s += __shfl_xor(s,32);
    float mean = s*(1.0f/128.0f);
    float e0=v0-mean, e1=v1-mean;
    float q = e0*e0+e1*e1;
    q += __shfl_xor(q,1); q += __shfl_xor(q,2); q += __shfl_xor(q,4);
    q += __shfl_xor(q,8); q += __shfl_xor(q,16); q += __shfl_xor(q,32);
    float rinv = rsqrtf(q*(1.0f/128.0f)+1e-5f);
    unsigned int pk2 = ((unsigned int)f2b(e1*rinv*gv.y+bv.y)<<16)
                     |  (unsigned int)f2b(e0*rinv*gv.x+bv.x);
    *(unsigned int*)&lns[idx] = pk2;
  }
}

// ---------------- gate (+f2 split-K reduce): one wave, 2 rows, shared wdyn loads ----------------
__global__ __launch_bounds__(64) void gate_kernel(const float* __restrict__ x3p,
    const float* __restrict__ b_f2, const float* __restrict__ x2,
    const float* __restrict__ x0, const ushort_t* __restrict__ wdyn,
    const float* __restrict__ b_dyn, float* __restrict__ out){
  int n0 = blockIdx.x*2;
  int l = threadIdx.x;
  int d0 = 2*l, d1 = 2*l+1;
  __shared__ float sA[2][128];
  __shared__ float sR[2][128];
  float a0[2], a1[2], r0[2], r1[2];
  float2 bb = *(const float2*)&b_f2[d0];
  #pragma unroll
  for (int rr=0;rr<2;++rr){
    size_t idx = (size_t)(n0+rr)*128 + d0;
    float2 p0v = *(const float2*)&x3p[idx];
    float2 p1v = *(const float2*)&x3p[524288+idx];
    float2 p2v = *(const float2*)&x3p[1048576+idx];
    float2 p3v = *(const float2*)&x3p[1572864+idx];
    float2 xv = *(const float2*)&x2[idx];
    float2 rv = *(const float2*)&x0[idx];
    a0[rr] = p0v.x+p1v.x+p2v.x+p3v.x+bb.x+xv.x;
    a1[rr] = p0v.y+p1v.y+p2v.y+p3v.y+bb.y+xv.y;
    r0[rr]=rv.x; r1[rr]=rv.y;
    sA[rr][d0]=a0[rr]; sA[rr][d1]=a1[rr];
    sR[rr][d0]=rv.x;  sR[rr][d1]=rv.y;
  }
  __syncthreads();
  float2 bd = *(const float2*)&b_dyn[d0];
  float g0[2], g1[2];
  g0[0]=bd.x; g0[1]=bd.x; g1[0]=bd.y; g1[1]=bd.y;
  for (int k=0;k<128;++k){
    unsigned int wv = *(const unsigned int*)&wdyn[(size_t)k*128 + d0];
    float w0=b2f((ushort_t)(wv&0xffffu)), w1=b2f((ushort_t)(wv>>16));
    #pragma unroll
    for (int rr=0;rr<2;++rr){
      float sk = sA[rr][k];
      g0[rr]+=sk*w0; g1[rr]+=sk*w1;
    }
  }
  for (int k=0;k<128;++k){
    unsigned int wv = *(const unsigned int*)&wdyn[(size_t)(128+k)*128 + d0];
    float w0=b2f((ushort_t)(wv&0xffffu)), w1=b2f((ushort_t)(wv>>16));
    #pragma unroll
    for (int rr=0;rr<2;++rr){
      float sk = sR[rr][k];
      g0[rr]+=sk*w0; g1[rr]+=sk*w1;
    }
  }
  #pragma unroll
  for (int rr=0;rr<2;++rr){
    size_t idx=(size_t)(n0+rr)*128 + d0;
    float gg0=1.0f/(1.0f+__expf(-g0[rr]));
    float gg1=1.0f/(1.0f+__expf(-g1[rr]));
    float v0=a0[rr]*gg0 + r0[rr]*(1.0f-gg0);
    float v1=a1[rr]*gg1 + r1[rr]*(1.0f-gg1);
    *(float2*)&out[idx]=make_float2(v0,v1);
  }
}

extern "C" void kernel_launch(void* const* d_in, const int* in_sizes, int n_in,
                              void* d_out, int out_size, void* d_ws, size_t ws_size,
                              hipStream_t stream) {
  const float* x    =(const float*)d_in[0];
  const int*   ei   =(const int*)  d_in[1];
  const float* eattr=(const float*)d_in[2];
  const float* n1g=(const float*)d_in[3], *n1b=(const float*)d_in[4];
  const float* n2g=(const float*)d_in[5], *n2b=(const float*)d_in[6];
  const float* n3g=(const float*)d_in[7], *n3b=(const float*)d_in[8];
  const float* w_qkv=(const float*)d_in[9],  *b_qkv=(const float*)d_in[10];
  const float* w_o  =(const float*)d_in[11], *b_o  =(const float*)d_in[12];
  const float* w_q  =(const float*)d_in[13], *b_q  =(const float*)d_in[14];
  const float* w_k  =(const float*)d_in[15], *b_k  =(const float*)d_in[16];
  const float* w_v  =(const float*)d_in[17], *b_v  =(const float*)d_in[18];
  const float* w_e  =(const float*)d_in[19], *b_e  =(const float*)d_in[20];
  const float* w_s  =(const float*)d_in[21], *b_s  =(const float*)d_in[22];
  const float* w_beta=(const float*)d_in[23];
  const float* w_f1 =(const float*)d_in[24], *b_f1=(const float*)d_in[25];
  const float* w_f2 =(const float*)d_in[26], *b_f2=(const float*)d_in[27];
  const float* w_dyn=(const float*)d_in[28], *b_dyn=(const float*)d_in[29];
  float* out=(float*)d_out;
  float* ws=(float*)d_ws;

  // ---- arena (float units); peak ~9.37M fu = 37.5 MiB ----
  float* X1    = ws + 0;        // 524288
  float* X2    = ws + 524288;   // 524288 (ATTN alias; PACK/PACKE/BQKV overlay while X2 dead)
  ushort_t* LNS = (ushort_t*)(ws + 1048576); // bf16 4096x128 -> 1310720
  float* PART  = ws + 1310720;  // 524288 -> 1835008
  float* ALPHA = ws + 1835008;  // 524288 -> 2359296 (CSR-position indexed)
  int*   ROWS  = (int*)(ws + 2359296);  // 4097 -> pad 2363456
  int*   CURS  = (int*)(ws + 2363456);  // -> 2367552
  int*   CSR   = (int*)(ws + 2367552);  // -> 2433088
  int*   COUNT = (int*)(ws + 2433088);  // -> 2437184
  // PACK/PACKE: overlay X2 region (dead between mgemm(w_o) and combine)
  int*   PACK  = (int*)(ws + 524288);   // 65536 ints -> fu 589824
  int*   PACKE = (int*)(ws + 589824);   // 65536 ints -> fu 655360
  // BQKV: 384 floats at X2 region tail; live only megawcvt -> qkv mgemm
  float* BQKV  = ws + 1048576 - 512;
  ushort_t* WBqkv = (ushort_t*)(ws + 2437184);
  ushort_t* WBo   = (ushort_t*)(ws + 2461760);
  ushort_t* WBG   = (ushort_t*)(ws + 2469952);
  ushort_t* WETB  = (ushort_t*)(ws + 2601024);
  ushort_t* WBf1  = (ushort_t*)(ws + 2666560);
  ushort_t* WBf2  = (ushort_t*)(ws + 2797632);
  ushort_t* WCAT  = (ushort_t*)(ws + 2928704);
  float* BCAT  = ws + 3059776;
  ushort_t* WDYN = (ushort_t*)(ws + 3061824);
  // BIG overlay at 3078208
  _Float16* QKVH  = (_Float16*)(ws + 3078208);
  _Float16* VT    = (_Float16*)(ws + 3864640);
  ushort_t* QKVSG = (ushort_t*)(ws + 3078208);
  ushort_t* SEAGG = (ushort_t*)(ws + 3078208);
  ushort_t* MID   = (ushort_t*)(ws + 3078208);
  ushort_t* T     = (ushort_t*)(ws + 7272512);
  float* CORRP = ws + 7272512;
  float* X3P   = ws + 7272512;
  float* ATTN  = X2;

  megawcvt_kernel<<<1256,256,0,stream>>>(w_qkv,w_o,w_q,w_k,w_v,w_e,w_f1,w_f2,
                                         b_q,b_k,w_dyn,b_qkv,
                                         WBqkv,WBo,WBG,WETB,WBf1,WBf2,WCAT,BCAT,WDYN,COUNT,BQKV);

  // ---- block 1: LN1 (+edge count) + dense MHA (V^T + CSR scan fused into QKV GEMM) ----
  ln_kernel<<<1024,256,0,stream>>>(x, n1g, n1b, LNS, ei, COUNT, nullptr,nullptr,nullptr,nullptr);
  mgemm_kernel<1,2,1><<<dim3(7,32,1),256,0,stream>>>(LNS,128,0, WBqkv,128,0, BQKV, nullptr, QKVH,384,0, 128, 0, VT, COUNT, ROWS, CURS);
  flash_kernel<<<dim3(64,8),512,0,stream>>>(QKVH, VT, ATTN);
  mgemm_kernel<0,0,0><<<dim3(2,32,1),256,0,stream>>>(ATTN,128,0, WBo,128,0, b_o, x, X1,128,0, 128, 0, nullptr, nullptr,nullptr,nullptr);

  // ---- block 2: LN2 (+CSR scatter) + TransformerConv ----
  ln_kernel<<<1280,256,0,stream>>>(X1, n2g, n2b, LNS, ei, nullptr, CURS, CSR, PACK, PACKE);
  mgemm_kernel<1,1,0><<<dim3(32,32,1),256,0,stream>>>(LNS,128,0, WBG,128,0, BCAT, nullptr, QKVSG,2048,0, 128, 0, nullptr, nullptr,nullptr,nullptr);
  mgemm_kernel<1,1,0><<<dim3(2,32,8),256,0,stream>>>(QKVSG,2048,128, WETB,128,16384, nullptr, nullptr, T,1024,128, 128, 0, nullptr, nullptr,nullptr,nullptr);
  alpha_kernel<<<8192,256,0,stream>>>(eattr, QKVSG, T, CSR, PACK, ALPHA);
  agg1_kernel<<<NN,256,0,stream>>>(LNS, eattr, ALPHA, ROWS, PACKE, b_e, b_v, SEAGG, PART);
  mgemm_kernel<1,0,0><<<dim3(2,32,4),256,0,stream>>>(SEAGG,2048,512, WCAT,2048,512, nullptr, nullptr, CORRP,128,524288, 512, 0, nullptr, nullptr,nullptr,nullptr);
  combine_kernel<<<2048,64,0,stream>>>(X2, CORRP, PART, LNS, w_s, b_s, X1, w_beta, n3g, n3b);

  // ---- block 3: FFN (LN3 fused into combine -> LNS) ----
  mgemm_kernel<1,1,0><<<dim3(32,32,1),256,0,stream>>>(LNS,128,0, WBf1,128,0, b_f1, nullptr, MID,2048,0, 128, 1, nullptr, nullptr,nullptr,nullptr);
  mgemm_kernel<1,0,0><<<dim3(2,32,4),256,0,stream>>>(MID,2048,512, WBf2,2048,512, nullptr, nullptr, X3P,128,524288, 512, 0, nullptr, nullptr,nullptr,nullptr);

  // ---- block 4: FFN reduce + gated fusion ----
  gate_kernel<<<2048,64,0,stream>>>(X3P, b_f2, X2, x, WDYN, b_dyn, out);
}